// Round 2
// 475.893 us; speedup vs baseline: 1.0312x; 1.0312x over previous
//
#include <hip/hip_runtime.h>

typedef float f4 __attribute__((ext_vector_type(4)));  // nontemporal-compatible

// Every COEFFS row has at most 2 nonzero entries. Encode each pid as
// (src plane A, coeff A, src plane B, coeff B); plane index 0..3 maps to
// {hearts[...,0], hearts[...,1], rects[...,0], rects[...,1]}.
// Single-source pids (0,1) get cb = 0 and skip the B load (wave-uniform).
//
//   pid : COEFFS          -> A, cA, B, cB
//   0   : { 1, 0, 0, 0}   -> h0,+1, -, 0
//   1   : { 0, 0, 1, 0}   -> r0,+1, -, 0
//   2   : { 1, 0, 1, 0}   -> h0,+1, r0,+1
//   3   : { 1, 1, 0, 0}   -> h0,+1, h1,+1
//   4   : { 0, 0, 1, 1}   -> r0,+1, r1,+1
//   5   : { 1,-1, 0, 0}   -> h0,+1, h1,-1
//   6   : { 1, 0,-1, 0}   -> h0,+1, r0,-1
//   7   : {-1, 0, 1, 0}   -> h0,-1, r0,+1
//   8   : { 0, 0, 1,-1}   -> r0,+1, r1,-1
__device__ __constant__ int   SRC_A[9] = {0, 2, 0, 0, 2, 0, 0, 0, 2};
__device__ __constant__ float CF_A [9] = {1.f, 1.f, 1.f, 1.f, 1.f, 1.f, 1.f, -1.f, 1.f};
__device__ __constant__ int   SRC_B[9] = {0, 2, 2, 1, 3, 1, 2, 2, 3};
__device__ __constant__ float CF_B [9] = {0.f, 0.f, 1.f, 1.f, 1.f, -1.f, -1.f, 1.f, -1.f};

// One block per (b,t) image. Image = 64*64 = 4096 floats = 1024 float4;
// 256 threads x 4 float4 each. Streams have zero reuse -> nontemporal.
__global__ __launch_bounds__(256) void gen_obs_kernel(
    const int* __restrict__ pid,
    const f4*  __restrict__ hearts,   // (8192, 2, 1024) in float4 units
    const f4*  __restrict__ rects,    // (8192, 2, 1024)
    f4*        __restrict__ out)      // (8192, 1024)
{
    const int bt = blockIdx.x;           // 0..8191
    const int p  = pid[bt];

    const int   sa = SRC_A[p];
    const int   sb = SRC_B[p];
    const float ca = CF_A[p];
    const float cb = CF_B[p];

    // 32-bit offsets: max index 8191*2048 + 2047 < 2^24, fits easily.
    const unsigned in_base  = (unsigned)bt * 2048u;  // 2 planes * 1024 float4
    const unsigned out_base = (unsigned)bt * 1024u;

    const f4* __restrict__ baseA =
        (sa < 2 ? hearts : rects) + (in_base + (unsigned)(sa & 1) * 1024u);
    const f4* __restrict__ baseB =
        (sb < 2 ? hearts : rects) + (in_base + (unsigned)(sb & 1) * 1024u);
    const bool hasB = (cb != 0.f);       // wave-uniform (pid uniform per block)

    #pragma unroll
    for (int k = 0; k < 4; ++k) {
        const int pix = (int)threadIdx.x + k * 256;   // 0..1023

        f4 a = __builtin_nontemporal_load(&baseA[pix]);
        f4 acc = ca * a;

        if (hasB) {
            f4 b = __builtin_nontemporal_load(&baseB[pix]);
            acc += cb * b;
        }

        f4 o;
        o.x = fminf(fmaxf(acc.x, 0.f), 1.f);
        o.y = fminf(fmaxf(acc.y, 0.f), 1.f);
        o.z = fminf(fmaxf(acc.z, 0.f), 1.f);
        o.w = fminf(fmaxf(acc.w, 0.f), 1.f);
        __builtin_nontemporal_store(o, &out[out_base + pix]);
    }
}

extern "C" void kernel_launch(void* const* d_in, const int* in_sizes, int n_in,
                              void* d_out, int out_size, void* d_ws, size_t ws_size,
                              hipStream_t stream) {
    const int* pid    = (const int*)d_in[0];
    const f4*  hearts = (const f4*)d_in[1];
    const f4*  rects  = (const f4*)d_in[2];
    f4*        out    = (f4*)d_out;

    const int n_bt = in_sizes[0];   // 128*64 = 8192
    gen_obs_kernel<<<n_bt, 256, 0, stream>>>(pid, hearts, rects, out);
}